// Round 1
// baseline (696.270 us; speedup 1.0000x reference)
//
#include <hip/hip_runtime.h>

#define L_SEQ 2048
#define BATCH 16
#define DDIM  1024
#define MDIM  (L_SEQ * BATCH)   // 32768
#define NDIM  (3 * DDIM)        // 3072
#define KDIM  DDIM              // 1024
#define CH    (BATCH * DDIM)    // 16384

typedef __attribute__((ext_vector_type(8))) short short8;
typedef __attribute__((ext_vector_type(4))) float f32x4;

static __device__ __forceinline__ unsigned short f2bf(float f) {
  unsigned int u = __builtin_bit_cast(unsigned int, f);
  unsigned int lsb = (u >> 16) & 1u;
  u += 0x7fffu + lsb;
  return (unsigned short)(u >> 16);
}
static __device__ __forceinline__ float bf2f(unsigned short s) {
  unsigned int u = ((unsigned int)s) << 16;
  return __builtin_bit_cast(float, u);
}

static __device__ __forceinline__ void gll16(const void* g, void* l) {
  __builtin_amdgcn_global_load_lds(
      (const __attribute__((address_space(1))) unsigned int*)g,
      (__attribute__((address_space(3))) unsigned int*)l, 16, 0, 0);
}

// ---- converters ----------------------------------------------------------

__global__ void k_convert_x(const float4* __restrict__ x, ushort4* __restrict__ xb, int n4) {
  int i = blockIdx.x * blockDim.x + threadIdx.x;
  int stride = gridDim.x * blockDim.x;
  for (; i < n4; i += stride) {
    float4 v = x[i];
    ushort4 o;
    o.x = f2bf(v.x); o.y = f2bf(v.y); o.z = f2bf(v.z); o.w = f2bf(v.w);
    xb[i] = o;
  }
}

// Wb[n][k] = bf16( W[k][colmap(n)] ), colmap groups {xt, f, r} into contiguous col ranges
__global__ void k_convert_w(const float* __restrict__ w, unsigned short* __restrict__ wb) {
  int gid = blockIdx.x * 256 + threadIdx.x;   // 3072*1024 total
  int k = gid & (KDIM - 1);
  int n = gid >> 10;
  int col = (n < DDIM) ? 3 * n : (n < 2 * DDIM) ? 3 * (n - DDIM) + 1 : 3 * (n - 2 * DDIM) + 2;
  wb[gid] = f2bf(w[(size_t)k * NDIM + col]);
}

// ---- GEMM: out[M][3d] in permuted space; epilogue splits into xt/f/r -----

__global__ __launch_bounds__(256) void k_gemm(
    const unsigned short* __restrict__ xb,   // [M][K] bf16
    const unsigned short* __restrict__ wb,   // [N][K] bf16 (pre-transposed+permuted)
    const float* __restrict__ bias,          // [2d]
    float* __restrict__ outxt,               // d_out h-region, [M][d] fp32 (scratch: x_tilde)
    unsigned short* __restrict__ fbuf,       // [M][d] bf16
    unsigned short* __restrict__ rbuf) {     // [M][d] bf16
  __shared__ char As[128 * 64 * 2];
  __shared__ char Bs[128 * 64 * 2];

  const int tid  = threadIdx.x;
  const int lane = tid & 63;
  const int wid  = tid >> 6;
  const int wr   = wid >> 1;
  const int wc   = wid & 1;
  const int rowBase = blockIdx.y * 128;
  const int colBase = blockIdx.x * 128;

  f32x4 acc[4][4];
#pragma unroll
  for (int mi = 0; mi < 4; ++mi)
#pragma unroll
    for (int ni = 0; ni < 4; ++ni)
      acc[mi][ni] = (f32x4){0.f, 0.f, 0.f, 0.f};

  const char* axb = (const char*)xb;
  const char* bwb = (const char*)wb;

  for (int kt = 0; kt < KDIM / 64; ++kt) {
    // stage A+B panels: linear LDS dest, XOR-swizzled global source
#pragma unroll
    for (int i = 0; i < 4; ++i) {
      int q = (i * 256 + tid) * 16;           // linear byte in 16KB panel
      int r = q >> 7;                          // panel row (0..127)
      int c = q & 127;                         // byte col within 128B row
      int csrc = c ^ ((r & 7) << 4);           // inverse swizzle on source
      const char* ga = axb + (size_t)(rowBase + r) * 2048 + kt * 128 + csrc;
      const char* gb = bwb + (size_t)(colBase + r) * 2048 + kt * 128 + csrc;
      char* la = As + (i * 256 + wid * 64) * 16;   // wave-uniform base + lane*16
      char* lb = Bs + (i * 256 + wid * 64) * 16;
      gll16(ga, la);
      gll16(gb, lb);
    }
    __syncthreads();

#pragma unroll
    for (int ks = 0; ks < 2; ++ks) {
      short8 a[4], b[4];
      const int cb = ks * 64 + ((lane >> 4) << 4);  // byte col of this lane's 8 bf16
#pragma unroll
      for (int mi = 0; mi < 4; ++mi) {
        int rloc = wr * 64 + mi * 16 + (lane & 15);
        a[mi] = *(const short8*)(As + rloc * 128 + (cb ^ ((rloc & 7) << 4)));
      }
#pragma unroll
      for (int ni = 0; ni < 4; ++ni) {
        int cloc = wc * 64 + ni * 16 + (lane & 15);
        b[ni] = *(const short8*)(Bs + cloc * 128 + (cb ^ ((cloc & 7) << 4)));
      }
#pragma unroll
      for (int mi = 0; mi < 4; ++mi)
#pragma unroll
        for (int ni = 0; ni < 4; ++ni)
          acc[mi][ni] = __builtin_amdgcn_mfma_f32_16x16x32_bf16(a[mi], b[ni], acc[mi][ni], 0, 0, 0);
    }
    __syncthreads();
  }

  // epilogue: region 0 -> x_tilde (fp32 to d_out), 1 -> forget, 2 -> reset
  const int region = colBase >> 10;   // col tile fully inside one region (128 | 1024)
#pragma unroll
  for (int mi = 0; mi < 4; ++mi) {
    int growb = rowBase + wr * 64 + mi * 16 + ((lane >> 4) << 2);
#pragma unroll
    for (int ni = 0; ni < 4; ++ni) {
      int gcol = colBase + wc * 64 + ni * 16 + (lane & 15);
      f32x4 v = acc[mi][ni];
      if (region == 0) {
#pragma unroll
        for (int i = 0; i < 4; ++i)
          outxt[(size_t)(growb + i) * DDIM + gcol] = v[i];
      } else {
        float bv = bias[gcol - DDIM];
        int j = gcol - region * DDIM;
        unsigned short* dst = (region == 1) ? fbuf : rbuf;
#pragma unroll
        for (int i = 0; i < 4; ++i) {
          float s = 1.0f / (1.0f + __expf(-(v[i] + bv)));
          dst[(size_t)(growb + i) * DDIM + j] = f2bf(s);
        }
      }
    }
  }
}

// ---- sequential scan over L, one thread per (b, j) channel ---------------

__global__ __launch_bounds__(256) void k_scan(
    const float* __restrict__ x,
    const float* __restrict__ c0,
    const unsigned short* __restrict__ fbuf,
    const unsigned short* __restrict__ rbuf,
    float* out) {                               // d_out: [L][CH] h (xt on entry), then [CH] c_last
  int ch = blockIdx.x * 256 + threadIdx.x;      // 0..16383
  float c = c0[ch];
  for (int t0 = 0; t0 < L_SEQ; t0 += 8) {
    float xtv[8], xv[8], fv[8], rv[8];
#pragma unroll
    for (int u = 0; u < 8; ++u) {
      size_t idx = (size_t)(t0 + u) * CH + ch;
      xtv[u] = out[idx];
      fv[u] = bf2f(fbuf[idx]);
      rv[u] = bf2f(rbuf[idx]);
      xv[u] = x[idx];
    }
    float hv[8];
#pragma unroll
    for (int u = 0; u < 8; ++u) {
      c = (c - xtv[u]) * fv[u] + xtv[u];
      float e = __expf(-2.0f * fabsf(c));
      float g = (1.0f - e) / (1.0f + e);
      g = copysignf(g, c);
      hv[u] = (g - xv[u]) * rv[u] + xv[u];
    }
#pragma unroll
    for (int u = 0; u < 8; ++u)
      out[(size_t)(t0 + u) * CH + ch] = hv[u];
  }
  out[(size_t)L_SEQ * CH + ch] = c;
}

// ---- launch --------------------------------------------------------------

extern "C" void kernel_launch(void* const* d_in, const int* in_sizes, int n_in,
                              void* d_out, int out_size, void* d_ws, size_t ws_size,
                              hipStream_t stream) {
  const float* x    = (const float*)d_in[0];
  const float* w    = (const float*)d_in[1];
  const float* bias = (const float*)d_in[2];
  const float* c0   = (const float*)d_in[3];
  float* out = (float*)d_out;
  char* ws = (char*)d_ws;

  unsigned short* xb   = (unsigned short*)(ws);                  // 64 MiB
  unsigned short* wb   = (unsigned short*)(ws + 67108864);       //  6 MiB
  unsigned short* fbuf = (unsigned short*)(ws + 73400320);       // 64 MiB
  unsigned short* rbuf = (unsigned short*)(ws + 140509184);      // 64 MiB

  k_convert_x<<<2048, 256, 0, stream>>>((const float4*)x, (ushort4*)xb, MDIM * KDIM / 4);
  k_convert_w<<<(NDIM * KDIM) / 256, 256, 0, stream>>>(w, wb);

  dim3 ggrid(NDIM / 128, MDIM / 128);
  k_gemm<<<ggrid, 256, 0, stream>>>(xb, wb, bias, out, fbuf, rbuf);

  k_scan<<<CH / 256, 256, 0, stream>>>(x, c0, fbuf, rbuf, out);
}

// Round 2
// 411.013 us; speedup vs baseline: 1.6940x; 1.6940x over previous
//
#include <hip/hip_runtime.h>

#define L_SEQ 2048
#define BATCH 16
#define DDIM  1024
#define MDIM  (L_SEQ * BATCH)   // 32768
#define NDIM  (3 * DDIM)        // 3072
#define KDIM  DDIM              // 1024
#define CH    (BATCH * DDIM)    // 16384
#define NSEG  32
#define SEGL  64                // L_SEQ / NSEG

typedef __attribute__((ext_vector_type(8))) short short8;
typedef __attribute__((ext_vector_type(4))) float f32x4;

static __device__ __forceinline__ unsigned short f2bf(float f) {
  unsigned int u = __builtin_bit_cast(unsigned int, f);
  unsigned int lsb = (u >> 16) & 1u;
  u += 0x7fffu + lsb;
  return (unsigned short)(u >> 16);
}
static __device__ __forceinline__ float bf2f(unsigned short s) {
  unsigned int u = ((unsigned int)s) << 16;
  return __builtin_bit_cast(float, u);
}

static __device__ __forceinline__ void gll16(const void* g, void* l) {
  __builtin_amdgcn_global_load_lds(
      (const __attribute__((address_space(1))) unsigned int*)g,
      (__attribute__((address_space(3))) unsigned int*)l, 16, 0, 0);
}

// ---- converters ----------------------------------------------------------

__global__ void k_convert_x(const float4* __restrict__ x, ushort4* __restrict__ xb, int n4) {
  int i = blockIdx.x * blockDim.x + threadIdx.x;
  int stride = gridDim.x * blockDim.x;
  for (; i < n4; i += stride) {
    float4 v = x[i];
    ushort4 o;
    o.x = f2bf(v.x); o.y = f2bf(v.y); o.z = f2bf(v.z); o.w = f2bf(v.w);
    xb[i] = o;
  }
}

// Wb[n][k] = bf16( W[k][colmap(n)] ): regions {xt, f, r} -> contiguous col ranges
__global__ void k_convert_w(const float* __restrict__ w, unsigned short* __restrict__ wb) {
  int gid = blockIdx.x * 256 + threadIdx.x;   // 3072*1024 total
  int k = gid & (KDIM - 1);
  int n = gid >> 10;
  int col = (n < DDIM) ? 3 * n : (n < 2 * DDIM) ? 3 * (n - DDIM) + 1 : 3 * (n - 2 * DDIM) + 2;
  wb[gid] = f2bf(w[(size_t)k * NDIM + col]);
}

// ---- GEMM: 256x256 tile, BK=32, 8 waves, 4-buffer counted-vmcnt pipeline -

#define MFMA16(QM)                                                             \
  acc[(QM)*4+0][0] = __builtin_amdgcn_mfma_f32_16x16x32_bf16(a0, b0, acc[(QM)*4+0][0], 0, 0, 0); \
  acc[(QM)*4+0][1] = __builtin_amdgcn_mfma_f32_16x16x32_bf16(a0, b1, acc[(QM)*4+0][1], 0, 0, 0); \
  acc[(QM)*4+0][2] = __builtin_amdgcn_mfma_f32_16x16x32_bf16(a0, b2, acc[(QM)*4+0][2], 0, 0, 0); \
  acc[(QM)*4+0][3] = __builtin_amdgcn_mfma_f32_16x16x32_bf16(a0, b3, acc[(QM)*4+0][3], 0, 0, 0); \
  acc[(QM)*4+1][0] = __builtin_amdgcn_mfma_f32_16x16x32_bf16(a1, b0, acc[(QM)*4+1][0], 0, 0, 0); \
  acc[(QM)*4+1][1] = __builtin_amdgcn_mfma_f32_16x16x32_bf16(a1, b1, acc[(QM)*4+1][1], 0, 0, 0); \
  acc[(QM)*4+1][2] = __builtin_amdgcn_mfma_f32_16x16x32_bf16(a1, b2, acc[(QM)*4+1][2], 0, 0, 0); \
  acc[(QM)*4+1][3] = __builtin_amdgcn_mfma_f32_16x16x32_bf16(a1, b3, acc[(QM)*4+1][3], 0, 0, 0); \
  acc[(QM)*4+2][0] = __builtin_amdgcn_mfma_f32_16x16x32_bf16(a2, b0, acc[(QM)*4+2][0], 0, 0, 0); \
  acc[(QM)*4+2][1] = __builtin_amdgcn_mfma_f32_16x16x32_bf16(a2, b1, acc[(QM)*4+2][1], 0, 0, 0); \
  acc[(QM)*4+2][2] = __builtin_amdgcn_mfma_f32_16x16x32_bf16(a2, b2, acc[(QM)*4+2][2], 0, 0, 0); \
  acc[(QM)*4+2][3] = __builtin_amdgcn_mfma_f32_16x16x32_bf16(a2, b3, acc[(QM)*4+2][3], 0, 0, 0); \
  acc[(QM)*4+3][0] = __builtin_amdgcn_mfma_f32_16x16x32_bf16(a3, b0, acc[(QM)*4+3][0], 0, 0, 0); \
  acc[(QM)*4+3][1] = __builtin_amdgcn_mfma_f32_16x16x32_bf16(a3, b1, acc[(QM)*4+3][1], 0, 0, 0); \
  acc[(QM)*4+3][2] = __builtin_amdgcn_mfma_f32_16x16x32_bf16(a3, b2, acc[(QM)*4+3][2], 0, 0, 0); \
  acc[(QM)*4+3][3] = __builtin_amdgcn_mfma_f32_16x16x32_bf16(a3, b3, acc[(QM)*4+3][3], 0, 0, 0);

#define BARRIER_FENCE() do {                    \
  __builtin_amdgcn_sched_barrier(0);            \
  __builtin_amdgcn_s_barrier();                 \
  asm volatile("" ::: "memory");                \
  __builtin_amdgcn_sched_barrier(0);            \
} while (0)

__global__ __launch_bounds__(512, 2) void k_gemm256(
    const unsigned short* __restrict__ xb,   // [M][K] bf16
    const unsigned short* __restrict__ wb,   // [N][K] bf16
    const float* __restrict__ bias,          // [2d]
    unsigned short* __restrict__ xtb,        // [M][d] bf16
    unsigned short* __restrict__ fbuf,       // [M][d] bf16
    unsigned short* __restrict__ rbuf) {     // [M][d] bf16
  __shared__ char LDS[131072];   // 4 buffers x (A 16KB + B 16KB)

  const int tid  = threadIdx.x;
  const int lane = tid & 63;
  const int wid  = tid >> 6;
  const int wr   = wid >> 2;     // 0..1
  const int wc   = wid & 3;      // 0..3

  // XCD-aware bijective swizzle: 1536 = 8 * 192
  int bid = blockIdx.x;
  int wg = (bid & 7) * 192 + (bid >> 3);
  int mt = wg / 12;
  int nt = wg - mt * 12;
  const int rowBase = mt * 256;
  const int colBase = nt * 256;

  // ds_read bases (chunk-permuted layout: pos = row*4 + (slot ^ ((row>>1)&3)))
  const int l15 = lane & 15;
  const int sl  = lane >> 4;
  const int ra0 = wr * 128 + l15;
  const int rb0 = wc * 64 + l15;
  const int aRd = ra0 * 64 + (sl ^ ((ra0 >> 1) & 3)) * 16;
  const int bRd = rb0 * 64 + (sl ^ ((rb0 >> 1) & 3)) * 16;

  // staging source bases (inverse permutation on global source, linear LDS dest)
  const int p0 = tid, p1 = 512 + tid;
  const int r0 = p0 >> 2, r1 = p1 >> 2;
  const int s0 = (p0 & 3) ^ ((r0 >> 1) & 3);
  const int s1 = (p1 & 3) ^ ((r1 >> 1) & 3);
  const char* srcA0 = (const char*)xb + (size_t)(rowBase + r0) * 2048 + s0 * 16;
  const char* srcA1 = (const char*)xb + (size_t)(rowBase + r1) * 2048 + s1 * 16;
  const char* srcB0 = (const char*)wb + (size_t)(colBase + r0) * 2048 + s0 * 16;
  const char* srcB1 = (const char*)wb + (size_t)(colBase + r1) * 2048 + s1 * 16;

  f32x4 acc[8][4];
#pragma unroll
  for (int i = 0; i < 8; ++i)
#pragma unroll
    for (int j = 0; j < 4; ++j)
      acc[i][j] = (f32x4){0.f, 0.f, 0.f, 0.f};

  // prologue: stage tiles 0 and 1
#pragma unroll
  for (int u = 0; u < 2; ++u) {
    char* ldsu = LDS + u * 32768;
    gll16(srcA0 + (size_t)u * 64, ldsu + wid * 1024);
    gll16(srcA1 + (size_t)u * 64, ldsu + 8192 + wid * 1024);
    gll16(srcB0 + (size_t)u * 64, ldsu + 16384 + wid * 1024);
    gll16(srcB1 + (size_t)u * 64, ldsu + 24576 + wid * 1024);
  }
  asm volatile("s_waitcnt vmcnt(4)" ::: "memory");
  __builtin_amdgcn_s_barrier();
  __builtin_amdgcn_sched_barrier(0);

#pragma unroll 4
  for (int t = 0; t < 32; ++t) {
    const int bi = t & 3;
    const int u = (t + 2) & 31;          // wrap-stage at the tail (harmless, keeps vmcnt uniform)
    char* Ab = LDS + bi * 32768;
    char* Bb = Ab + 16384;
    char* ldsu = LDS + ((t + 2) & 3) * 32768;

    // ---- phase 0: quadrant qm=0 ----
    short8 a0 = *(const short8*)(Ab + aRd);
    short8 a1 = *(const short8*)(Ab + aRd + 1024);
    short8 a2 = *(const short8*)(Ab + aRd + 2048);
    short8 a3 = *(const short8*)(Ab + aRd + 3072);
    short8 b0 = *(const short8*)(Bb + bRd);
    short8 b1 = *(const short8*)(Bb + bRd + 1024);
    short8 b2 = *(const short8*)(Bb + bRd + 2048);
    short8 b3 = *(const short8*)(Bb + bRd + 3072);
    gll16(srcA0 + (size_t)u * 64, ldsu + wid * 1024);
    gll16(srcA1 + (size_t)u * 64, ldsu + 8192 + wid * 1024);
    BARRIER_FENCE();
    __builtin_amdgcn_s_setprio(1);
    MFMA16(0)
    __builtin_amdgcn_s_setprio(0);
    BARRIER_FENCE();

    // ---- phase 1: quadrant qm=1 (B frags reused) ----
    a0 = *(const short8*)(Ab + aRd + 4096);
    a1 = *(const short8*)(Ab + aRd + 5120);
    a2 = *(const short8*)(Ab + aRd + 6144);
    a3 = *(const short8*)(Ab + aRd + 7168);
    gll16(srcB0 + (size_t)u * 64, ldsu + 16384 + wid * 1024);
    gll16(srcB1 + (size_t)u * 64, ldsu + 24576 + wid * 1024);
    BARRIER_FENCE();
    __builtin_amdgcn_s_setprio(1);
    MFMA16(1)
    __builtin_amdgcn_s_setprio(0);
    __builtin_amdgcn_sched_barrier(0);
    asm volatile("s_waitcnt vmcnt(4)" ::: "memory");  // tile t+1 fully landed; t+2 in flight
    BARRIER_FENCE();
  }

  // epilogue
  const int region = colBase >> 10;
#pragma unroll
  for (int qm = 0; qm < 2; ++qm) {
#pragma unroll
    for (int m = 0; m < 4; ++m) {
      int grow = rowBase + wr * 128 + qm * 64 + m * 16 + ((lane >> 4) << 2);
#pragma unroll
      for (int n = 0; n < 4; ++n) {
        int gcol = colBase + wc * 64 + n * 16 + (lane & 15);
        f32x4 v = acc[qm * 4 + m][n];
        if (region == 0) {
#pragma unroll
          for (int j = 0; j < 4; ++j)
            xtb[(size_t)(grow + j) * DDIM + gcol] = f2bf(v[j]);
        } else {
          float bv = bias[gcol - DDIM];
          unsigned short* dst = (region == 1) ? fbuf : rbuf;
          int lcol = gcol - (region << 10);
#pragma unroll
          for (int j = 0; j < 4; ++j) {
            float sg = 1.0f / (1.0f + __expf(-(v[j] + bv)));
            dst[(size_t)(grow + j) * DDIM + lcol] = f2bf(sg);
          }
        }
      }
    }
  }
}

// ---- segmented scan ------------------------------------------------------
// pass 1: per (segment, channel-pair) affine state a = prod f, b = scan from 0

__global__ __launch_bounds__(256) void k_scan1(
    const unsigned short* __restrict__ fbuf,
    const unsigned short* __restrict__ xtb,
    float4* __restrict__ AB) {
  int chp = blockIdx.x * 256 + threadIdx.x;       // 0..8191 channel pairs
  int seg = blockIdx.y;
  size_t base = (size_t)seg * SEGL * CH + chp * 2;
  const unsigned int* fp = (const unsigned int*)(fbuf + base);
  const unsigned int* xp = (const unsigned int*)(xtb + base);
  float a0 = 1.f, a1 = 1.f, b0 = 0.f, b1 = 0.f;
#pragma unroll 8
  for (int s = 0; s < SEGL; ++s) {
    unsigned int fv = fp[(size_t)s * (CH / 2)];
    unsigned int xv = xp[(size_t)s * (CH / 2)];
    float f0 = bf2f((unsigned short)fv), f1 = bf2f((unsigned short)(fv >> 16));
    float x0 = bf2f((unsigned short)xv), x1 = bf2f((unsigned short)(xv >> 16));
    b0 = (b0 - x0) * f0 + x0;  a0 *= f0;
    b1 = (b1 - x1) * f1 + x1;  a1 *= f1;
  }
  AB[(size_t)seg * (CH / 2) + chp] = (float4){a0, b0, a1, b1};
}

// pass 2: scan 32 segment states per channel; emit per-segment c_in and c_last

__global__ __launch_bounds__(256) void k_scan2(
    const float* __restrict__ c0,
    const float4* __restrict__ AB,
    float* __restrict__ Cin,
    float* __restrict__ clast) {
  int chp = blockIdx.x * 256 + threadIdx.x;       // 0..8191
  float2 cc = ((const float2*)c0)[chp];
  float ca = cc.x, cb = cc.y;
#pragma unroll
  for (int s = 0; s < NSEG; ++s) {
    ((float2*)Cin)[(size_t)s * (CH / 2) + chp] = (float2){ca, cb};
    float4 ab = AB[(size_t)s * (CH / 2) + chp];
    ca = ca * ab.x + ab.y;
    cb = cb * ab.z + ab.w;
  }
  ((float2*)clast)[chp] = (float2){ca, cb};
}

// pass 3: recompute c within segment from c_in; emit h

__global__ __launch_bounds__(256) void k_scan3(
    const float* __restrict__ x,
    const unsigned short* __restrict__ fbuf,
    const unsigned short* __restrict__ xtb,
    const unsigned short* __restrict__ rbuf,
    const float* __restrict__ Cin,
    float* __restrict__ h) {
  int chp = blockIdx.x * 256 + threadIdx.x;
  int seg = blockIdx.y;
  float2 cc = ((const float2*)Cin)[(size_t)seg * (CH / 2) + chp];
  float ca = cc.x, cb = cc.y;
  size_t base = (size_t)seg * SEGL * CH + chp * 2;
  const unsigned int* fp = (const unsigned int*)(fbuf + base);
  const unsigned int* tp = (const unsigned int*)(xtb + base);
  const unsigned int* rp = (const unsigned int*)(rbuf + base);
  const float2* xp = (const float2*)(x + base);
  float2* hp = (float2*)(h + base);
#pragma unroll 4
  for (int s = 0; s < SEGL; ++s) {
    unsigned int fv = fp[(size_t)s * (CH / 2)];
    unsigned int tv = tp[(size_t)s * (CH / 2)];
    unsigned int rv = rp[(size_t)s * (CH / 2)];
    float2 xv = xp[(size_t)s * (CH / 2)];
    float f0 = bf2f((unsigned short)fv), f1 = bf2f((unsigned short)(fv >> 16));
    float t0 = bf2f((unsigned short)tv), t1 = bf2f((unsigned short)(tv >> 16));
    float r0 = bf2f((unsigned short)rv), r1 = bf2f((unsigned short)(rv >> 16));
    ca = (ca - t0) * f0 + t0;
    cb = (cb - t1) * f1 + t1;
    float e0 = __expf(-2.f * fabsf(ca));
    float e1 = __expf(-2.f * fabsf(cb));
    float g0 = copysignf((1.f - e0) / (1.f + e0), ca);
    float g1 = copysignf((1.f - e1) / (1.f + e1), cb);
    float h0 = (g0 - xv.x) * r0 + xv.x;
    float h1 = (g1 - xv.y) * r1 + xv.y;
    hp[(size_t)s * (CH / 2)] = (float2){h0, h1};
  }
}

// ---- launch --------------------------------------------------------------

extern "C" void kernel_launch(void* const* d_in, const int* in_sizes, int n_in,
                              void* d_out, int out_size, void* d_ws, size_t ws_size,
                              hipStream_t stream) {
  const float* x    = (const float*)d_in[0];
  const float* w    = (const float*)d_in[1];
  const float* bias = (const float*)d_in[2];
  const float* c0   = (const float*)d_in[3];
  float* out = (float*)d_out;
  char* ws = (char*)d_ws;

  // ws layout (207.6 MB total):
  //   [0, 6.29MB): wb (GEMM weights)  -- after GEMM, reused as AB (4MB) + Cin (2MB)
  unsigned short* wb   = (unsigned short*)(ws);
  float4*         AB   = (float4*)(ws);
  float*          Cin  = (float*)(ws + 4194304);
  unsigned short* xtb  = (unsigned short*)(ws + 6291456);
  unsigned short* fbuf = (unsigned short*)(ws + 73400320);
  unsigned short* rbuf = (unsigned short*)(ws + 140509184);
  // xb (bf16 x, 64MB) lives in d_out's h region (dead until pass 3 rewrites it)
  unsigned short* xb = (unsigned short*)d_out;

  k_convert_x<<<2048, 256, 0, stream>>>((const float4*)x, (ushort4*)xb, MDIM * KDIM / 4);
  k_convert_w<<<(NDIM * KDIM) / 256, 256, 0, stream>>>(w, wb);

  k_gemm256<<<1536, 512, 0, stream>>>(xb, wb, bias, xtb, fbuf, rbuf);

  k_scan1<<<dim3(32, NSEG), 256, 0, stream>>>(fbuf, xtb, AB);
  k_scan2<<<32, 256, 0, stream>>>(c0, AB, Cin, out + (size_t)L_SEQ * CH);
  k_scan3<<<dim3(32, NSEG), 256, 0, stream>>>(x, fbuf, xtb, rbuf, Cin, out);
}

// Round 3
// 409.256 us; speedup vs baseline: 1.7013x; 1.0043x over previous
//
#include <hip/hip_runtime.h>

#define L_SEQ 2048
#define BATCH 16
#define DDIM  1024
#define MDIM  (L_SEQ * BATCH)   // 32768
#define NDIM  (3 * DDIM)        // 3072
#define KDIM  DDIM              // 1024
#define CH    (BATCH * DDIM)    // 16384
#define NSEG  32
#define SEGL  64                // L_SEQ / NSEG

typedef __attribute__((ext_vector_type(8))) short short8;
typedef __attribute__((ext_vector_type(4))) float f32x4;

static __device__ __forceinline__ unsigned short f2bf(float f) {
  unsigned int u = __builtin_bit_cast(unsigned int, f);
  unsigned int lsb = (u >> 16) & 1u;
  u += 0x7fffu + lsb;
  return (unsigned short)(u >> 16);
}
static __device__ __forceinline__ float bf2f(unsigned short s) {
  unsigned int u = ((unsigned int)s) << 16;
  return __builtin_bit_cast(float, u);
}

static __device__ __forceinline__ void gll16(const void* g, void* l) {
  __builtin_amdgcn_global_load_lds(
      (const __attribute__((address_space(1))) unsigned int*)g,
      (__attribute__((address_space(3))) unsigned int*)l, 16, 0, 0);
}

// ---- converters ----------------------------------------------------------

__global__ void k_convert_x(const float4* __restrict__ x, ushort4* __restrict__ xb, int n4) {
  int i = blockIdx.x * blockDim.x + threadIdx.x;
  int stride = gridDim.x * blockDim.x;
  for (; i < n4; i += stride) {
    float4 v = x[i];
    ushort4 o;
    o.x = f2bf(v.x); o.y = f2bf(v.y); o.z = f2bf(v.z); o.w = f2bf(v.w);
    xb[i] = o;
  }
}

// Wb[n][k] = bf16( W[k][colmap(n)] ): regions {xt, f, r} -> contiguous col ranges
__global__ void k_convert_w(const float* __restrict__ w, unsigned short* __restrict__ wb) {
  int gid = blockIdx.x * 256 + threadIdx.x;   // 3072*1024 total
  int k = gid & (KDIM - 1);
  int n = gid >> 10;
  int col = (n < DDIM) ? 3 * n : (n < 2 * DDIM) ? 3 * (n - DDIM) + 1 : 3 * (n - 2 * DDIM) + 2;
  wb[gid] = f2bf(w[(size_t)k * NDIM + col]);
}

// ---- GEMM: 256x256 tile, BK=32, 4-buffer, reg-pipelined LDS/MFMA overlap -

#define MFMA1(I, J, A, B) \
  acc[I][J] = __builtin_amdgcn_mfma_f32_16x16x32_bf16(A, B, acc[I][J], 0, 0, 0);

#define MFMAQ(BASE, A0, A1, A2, A3, B0, B1, B2, B3)  \
  MFMA1(BASE + 0, 0, A0, B0) MFMA1(BASE + 0, 1, A0, B1) \
  MFMA1(BASE + 0, 2, A0, B2) MFMA1(BASE + 0, 3, A0, B3) \
  MFMA1(BASE + 1, 0, A1, B0) MFMA1(BASE + 1, 1, A1, B1) \
  MFMA1(BASE + 1, 2, A1, B2) MFMA1(BASE + 1, 3, A1, B3) \
  MFMA1(BASE + 2, 0, A2, B0) MFMA1(BASE + 2, 1, A2, B1) \
  MFMA1(BASE + 2, 2, A2, B2) MFMA1(BASE + 2, 3, A2, B3) \
  MFMA1(BASE + 3, 0, A3, B0) MFMA1(BASE + 3, 1, A3, B1) \
  MFMA1(BASE + 3, 2, A3, B2) MFMA1(BASE + 3, 3, A3, B3)

// One K-tile (BK=32). P0: read cur mh1 A-frags, stage A(+2), MFMA(mh0).
// P1: stage B(+2), fence (vmcnt(4)+barrier), read NEXT tile mh0+B, MFMA(mh1).
#define TILE(J, X0, X1, X2, X3, Y0, Y1, Y2, Y3) do {                         \
  const char* Ab  = LDSc + (((J)) & 3) * 32768;                              \
  const char* AbN = LDSc + (((J) + 1) & 3) * 32768;                          \
  char* Sb = LDSc + (((J) + 2) & 3) * 32768;                                 \
  const int kbS = ((i * 4 + (J) + 2) & 31) * 64;                             \
  q0 = *(const short8*)(Ab + aRd + 4096);                                    \
  q1 = *(const short8*)(Ab + aRd + 5120);                                    \
  q2 = *(const short8*)(Ab + aRd + 6144);                                    \
  q3 = *(const short8*)(Ab + aRd + 7168);                                    \
  gll16(srcA0 + kbS, Sb + dstOff);                                           \
  gll16(srcA1 + kbS, Sb + 8192 + dstOff);                                    \
  __builtin_amdgcn_s_setprio(1);                                             \
  MFMAQ(0, p0, p1, p2, p3, X0, X1, X2, X3)                                   \
  __builtin_amdgcn_s_setprio(0);                                             \
  gll16(srcB0 + kbS, Sb + 16384 + dstOff);                                   \
  gll16(srcB1 + kbS, Sb + 24576 + dstOff);                                   \
  __builtin_amdgcn_sched_barrier(0);                                         \
  asm volatile("s_waitcnt vmcnt(4)" ::: "memory");                           \
  __builtin_amdgcn_s_barrier();                                              \
  __builtin_amdgcn_sched_barrier(0);                                         \
  p0 = *(const short8*)(AbN + aRd);                                          \
  p1 = *(const short8*)(AbN + aRd + 1024);                                   \
  p2 = *(const short8*)(AbN + aRd + 2048);                                   \
  p3 = *(const short8*)(AbN + aRd + 3072);                                   \
  Y0 = *(const short8*)(AbN + 16384 + bRd);                                  \
  Y1 = *(const short8*)(AbN + 16384 + bRd + 1024);                           \
  Y2 = *(const short8*)(AbN + 16384 + bRd + 2048);                           \
  Y3 = *(const short8*)(AbN + 16384 + bRd + 3072);                           \
  __builtin_amdgcn_s_setprio(1);                                             \
  MFMAQ(4, q0, q1, q2, q3, X0, X1, X2, X3)                                   \
  __builtin_amdgcn_s_setprio(0);                                             \
} while (0)

__global__ __launch_bounds__(512, 2) void k_gemm256(
    const unsigned short* __restrict__ xb,   // [M][K] bf16
    const unsigned short* __restrict__ wb,   // [N][K] bf16
    const float* __restrict__ bias,          // [2d]
    unsigned short* __restrict__ xtb,        // [M][d] bf16
    unsigned short* __restrict__ fbuf,       // [M][d] bf16
    unsigned short* __restrict__ rbuf) {     // [M][d] bf16
  __shared__ char LDS[131072];   // 4 buffers x (A 16KB + B 16KB)
  char* LDSc = LDS;

  const int tid  = threadIdx.x;
  const int lane = tid & 63;
  const int wid  = tid >> 6;
  const int wr   = wid >> 2;     // 0..1
  const int wc   = wid & 3;      // 0..3

  // XCD-aware bijective swizzle: 1536 = 8 * 192
  int bid = blockIdx.x;
  int wg = (bid & 7) * 192 + (bid >> 3);
  int mt = wg / 12;
  int nt = wg - mt * 12;
  const int rowBase = mt * 256;
  const int colBase = nt * 256;

  // ds_read bases (chunk-permuted layout: pos = row*4 + (slot ^ ((row>>1)&3)))
  const int l15 = lane & 15;
  const int sl  = lane >> 4;
  const int ra0 = wr * 128 + l15;
  const int rb0 = wc * 64 + l15;
  const int aRd = ra0 * 64 + (sl ^ ((ra0 >> 1) & 3)) * 16;
  const int bRd = rb0 * 64 + (sl ^ ((rb0 >> 1) & 3)) * 16;

  // staging source bases (inverse permutation on global source, linear LDS dest)
  const int p0i = tid, p1i = 512 + tid;
  const int r0 = p0i >> 2, r1 = p1i >> 2;
  const int s0 = (p0i & 3) ^ ((r0 >> 1) & 3);
  const int s1 = (p1i & 3) ^ ((r1 >> 1) & 3);
  const char* srcA0 = (const char*)xb + (size_t)(rowBase + r0) * 2048 + s0 * 16;
  const char* srcA1 = (const char*)xb + (size_t)(rowBase + r1) * 2048 + s1 * 16;
  const char* srcB0 = (const char*)wb + (size_t)(colBase + r0) * 2048 + s0 * 16;
  const char* srcB1 = (const char*)wb + (size_t)(colBase + r1) * 2048 + s1 * 16;
  const int dstOff = wid * 1024;

  f32x4 acc[8][4];
#pragma unroll
  for (int ii = 0; ii < 8; ++ii)
#pragma unroll
    for (int jj = 0; jj < 4; ++jj)
      acc[ii][jj] = (f32x4){0.f, 0.f, 0.f, 0.f};

  // prologue: stage tiles 0 and 1
#pragma unroll
  for (int u = 0; u < 2; ++u) {
    char* ldsu = LDSc + u * 32768;
    gll16(srcA0 + u * 64, ldsu + dstOff);
    gll16(srcA1 + u * 64, ldsu + 8192 + dstOff);
    gll16(srcB0 + u * 64, ldsu + 16384 + dstOff);
    gll16(srcB1 + u * 64, ldsu + 24576 + dstOff);
  }
  asm volatile("s_waitcnt vmcnt(4)" ::: "memory");
  __builtin_amdgcn_s_barrier();
  __builtin_amdgcn_sched_barrier(0);

  short8 p0, p1, p2, p3;   // A mh0 frags
  short8 q0, q1, q2, q3;   // A mh1 frags
  short8 e0, e1, e2, e3;   // B set (even tiles)
  short8 o0, o1, o2, o3;   // B set (odd tiles)

  // preload tile 0: mh0 A frags + B frags
  p0 = *(const short8*)(LDSc + aRd);
  p1 = *(const short8*)(LDSc + aRd + 1024);
  p2 = *(const short8*)(LDSc + aRd + 2048);
  p3 = *(const short8*)(LDSc + aRd + 3072);
  e0 = *(const short8*)(LDSc + 16384 + bRd);
  e1 = *(const short8*)(LDSc + 16384 + bRd + 1024);
  e2 = *(const short8*)(LDSc + 16384 + bRd + 2048);
  e3 = *(const short8*)(LDSc + 16384 + bRd + 3072);

  for (int i = 0; i < 8; ++i) {
    TILE(0, e0, e1, e2, e3, o0, o1, o2, o3);
    TILE(1, o0, o1, o2, o3, e0, e1, e2, e3);
    TILE(2, e0, e1, e2, e3, o0, o1, o2, o3);
    TILE(3, o0, o1, o2, o3, e0, e1, e2, e3);
  }
  asm volatile("s_waitcnt vmcnt(0)" ::: "memory");

  // epilogue: region 0 -> x_tilde (bf16), 1 -> forget, 2 -> reset
  const int region = colBase >> 10;
#pragma unroll
  for (int qm = 0; qm < 2; ++qm) {
#pragma unroll
    for (int m = 0; m < 4; ++m) {
      int grow = rowBase + wr * 128 + qm * 64 + m * 16 + ((lane >> 4) << 2);
#pragma unroll
      for (int n = 0; n < 4; ++n) {
        int gcol = colBase + wc * 64 + n * 16 + (lane & 15);
        f32x4 v = acc[qm * 4 + m][n];
        if (region == 0) {
#pragma unroll
          for (int j = 0; j < 4; ++j)
            xtb[(size_t)(grow + j) * DDIM + gcol] = f2bf(v[j]);
        } else {
          float bv = bias[gcol - DDIM];
          unsigned short* dst = (region == 1) ? fbuf : rbuf;
          int lcol = gcol - (region << 10);
#pragma unroll
          for (int j = 0; j < 4; ++j) {
            float sg = 1.0f / (1.0f + __expf(-(v[j] + bv)));
            dst[(size_t)(grow + j) * DDIM + lcol] = f2bf(sg);
          }
        }
      }
    }
  }
}

// ---- segmented scan ------------------------------------------------------
// pass 1: per (segment, channel-pair) affine state a = prod f, b = scan from 0

__global__ __launch_bounds__(256) void k_scan1(
    const unsigned short* __restrict__ fbuf,
    const unsigned short* __restrict__ xtb,
    float4* __restrict__ AB) {
  int chp = blockIdx.x * 256 + threadIdx.x;       // 0..8191 channel pairs
  int seg = blockIdx.y;
  size_t base = (size_t)seg * SEGL * CH + chp * 2;
  const unsigned int* fp = (const unsigned int*)(fbuf + base);
  const unsigned int* xp = (const unsigned int*)(xtb + base);
  float a0 = 1.f, a1 = 1.f, b0 = 0.f, b1 = 0.f;
#pragma unroll 8
  for (int s = 0; s < SEGL; ++s) {
    unsigned int fv = fp[(size_t)s * (CH / 2)];
    unsigned int xv = xp[(size_t)s * (CH / 2)];
    float f0 = bf2f((unsigned short)fv), f1 = bf2f((unsigned short)(fv >> 16));
    float x0 = bf2f((unsigned short)xv), x1 = bf2f((unsigned short)(xv >> 16));
    b0 = (b0 - x0) * f0 + x0;  a0 *= f0;
    b1 = (b1 - x1) * f1 + x1;  a1 *= f1;
  }
  AB[(size_t)seg * (CH / 2) + chp] = (float4){a0, b0, a1, b1};
}

// pass 2: scan 32 segment states per channel; emit per-segment c_in and c_last

__global__ __launch_bounds__(256) void k_scan2(
    const float* __restrict__ c0,
    const float4* __restrict__ AB,
    float* __restrict__ Cin,
    float* __restrict__ clast) {
  int chp = blockIdx.x * 256 + threadIdx.x;       // 0..8191
  float2 cc = ((const float2*)c0)[chp];
  float ca = cc.x, cb = cc.y;
#pragma unroll
  for (int s = 0; s < NSEG; ++s) {
    ((float2*)Cin)[(size_t)s * (CH / 2) + chp] = (float2){ca, cb};
    float4 ab = AB[(size_t)s * (CH / 2) + chp];
    ca = ca * ab.x + ab.y;
    cb = cb * ab.z + ab.w;
  }
  ((float2*)clast)[chp] = (float2){ca, cb};
}

// pass 3: recompute c within segment from c_in; emit h

__global__ __launch_bounds__(256) void k_scan3(
    const float* __restrict__ x,
    const unsigned short* __restrict__ fbuf,
    const unsigned short* __restrict__ xtb,
    const unsigned short* __restrict__ rbuf,
    const float* __restrict__ Cin,
    float* __restrict__ h) {
  int chp = blockIdx.x * 256 + threadIdx.x;
  int seg = blockIdx.y;
  float2 cc = ((const float2*)Cin)[(size_t)seg * (CH / 2) + chp];
  float ca = cc.x, cb = cc.y;
  size_t base = (size_t)seg * SEGL * CH + chp * 2;
  const unsigned int* fp = (const unsigned int*)(fbuf + base);
  const unsigned int* tp = (const unsigned int*)(xtb + base);
  const unsigned int* rp = (const unsigned int*)(rbuf + base);
  const float2* xp = (const float2*)(x + base);
  float2* hp = (float2*)(h + base);
#pragma unroll 4
  for (int s = 0; s < SEGL; ++s) {
    unsigned int fv = fp[(size_t)s * (CH / 2)];
    unsigned int tv = tp[(size_t)s * (CH / 2)];
    unsigned int rv = rp[(size_t)s * (CH / 2)];
    float2 xv = xp[(size_t)s * (CH / 2)];
    float f0 = bf2f((unsigned short)fv), f1 = bf2f((unsigned short)(fv >> 16));
    float t0 = bf2f((unsigned short)tv), t1 = bf2f((unsigned short)(tv >> 16));
    float r0 = bf2f((unsigned short)rv), r1 = bf2f((unsigned short)(rv >> 16));
    ca = (ca - t0) * f0 + t0;
    cb = (cb - t1) * f1 + t1;
    float e0 = __expf(-2.f * fabsf(ca));
    float e1 = __expf(-2.f * fabsf(cb));
    float g0 = copysignf((1.f - e0) / (1.f + e0), ca);
    float g1 = copysignf((1.f - e1) / (1.f + e1), cb);
    float h0 = (g0 - xv.x) * r0 + xv.x;
    float h1 = (g1 - xv.y) * r1 + xv.y;
    hp[(size_t)s * (CH / 2)] = (float2){h0, h1};
  }
}

// ---- launch --------------------------------------------------------------

extern "C" void kernel_launch(void* const* d_in, const int* in_sizes, int n_in,
                              void* d_out, int out_size, void* d_ws, size_t ws_size,
                              hipStream_t stream) {
  const float* x    = (const float*)d_in[0];
  const float* w    = (const float*)d_in[1];
  const float* bias = (const float*)d_in[2];
  const float* c0   = (const float*)d_in[3];
  float* out = (float*)d_out;
  char* ws = (char*)d_ws;

  // ws layout (207.6 MB total):
  //   [0, 6.29MB): wb (GEMM weights)  -- after GEMM, reused as AB (4MB) + Cin (2MB)
  unsigned short* wb   = (unsigned short*)(ws);
  float4*         AB   = (float4*)(ws);
  float*          Cin  = (float*)(ws + 4194304);
  unsigned short* xtb  = (unsigned short*)(ws + 6291456);
  unsigned short* fbuf = (unsigned short*)(ws + 73400320);
  unsigned short* rbuf = (unsigned short*)(ws + 140509184);
  // xb (bf16 x, 64MB) lives in d_out's h region (dead until pass 3 rewrites it)
  unsigned short* xb = (unsigned short*)d_out;

  k_convert_x<<<2048, 256, 0, stream>>>((const float4*)x, (ushort4*)xb, MDIM * KDIM / 4);
  k_convert_w<<<(NDIM * KDIM) / 256, 256, 0, stream>>>(w, wb);

  k_gemm256<<<1536, 512, 0, stream>>>(xb, wb, bias, xtb, fbuf, rbuf);

  k_scan1<<<dim3(32, NSEG), 256, 0, stream>>>(fbuf, xtb, AB);
  k_scan2<<<32, 256, 0, stream>>>(c0, AB, Cin, out + (size_t)L_SEQ * CH);
  k_scan3<<<dim3(32, NSEG), 256, 0, stream>>>(x, fbuf, xtb, rbuf, Cin, out);
}

// Round 4
// 408.627 us; speedup vs baseline: 1.7039x; 1.0015x over previous
//
#include <hip/hip_runtime.h>

#define L_SEQ 2048
#define BATCH 16
#define DDIM  1024
#define MDIM  (L_SEQ * BATCH)   // 32768
#define NDIM  (3 * DDIM)        // 3072
#define KDIM  DDIM              // 1024
#define CH    (BATCH * DDIM)    // 16384
#define NSEG  32
#define SEGL  64                // L_SEQ / NSEG

typedef __attribute__((ext_vector_type(8))) short short8;
typedef __attribute__((ext_vector_type(4))) float f32x4;

static __device__ __forceinline__ unsigned short f2bf(float f) {
  unsigned int u = __builtin_bit_cast(unsigned int, f);
  unsigned int lsb = (u >> 16) & 1u;
  u += 0x7fffu + lsb;
  return (unsigned short)(u >> 16);
}
static __device__ __forceinline__ float bf2f(unsigned short s) {
  unsigned int u = ((unsigned int)s) << 16;
  return __builtin_bit_cast(float, u);
}

static __device__ __forceinline__ void gll16(const void* g, void* l) {
  __builtin_amdgcn_global_load_lds(
      (const __attribute__((address_space(1))) unsigned int*)g,
      (__attribute__((address_space(3))) unsigned int*)l, 16, 0, 0);
}

// ---- converters ----------------------------------------------------------

__global__ void k_convert_x(const float4* __restrict__ x, ushort4* __restrict__ xb, int n4) {
  int i = blockIdx.x * blockDim.x + threadIdx.x;
  int stride = gridDim.x * blockDim.x;
  for (; i < n4; i += stride) {
    float4 v = x[i];
    ushort4 o;
    o.x = f2bf(v.x); o.y = f2bf(v.y); o.z = f2bf(v.z); o.w = f2bf(v.w);
    xb[i] = o;
  }
}

// Wb[n][k] = bf16( W[k][colmap(n)] ): regions {xt, f, r} -> contiguous col ranges
__global__ void k_convert_w(const float* __restrict__ w, unsigned short* __restrict__ wb) {
  int gid = blockIdx.x * 256 + threadIdx.x;   // 3072*1024 total
  int k = gid & (KDIM - 1);
  int n = gid >> 10;
  int col = (n < DDIM) ? 3 * n : (n < 2 * DDIM) ? 3 * (n - DDIM) + 1 : 3 * (n - 2 * DDIM) + 2;
  wb[gid] = f2bf(w[(size_t)k * NDIM + col]);
}

// ---- GEMM: 256x256, BK=64, 8 waves, m201-style 4-phase counted-vmcnt -----
// LDS: 2 buffers x 64KB; buffer = { A_kb0 16K | A_kb1 16K | B_kb0 16K | B_kb1 16K }
// each 16K subtile: 256 rows x 64B, 16B-slot permutation slot^((row>>1)&3) (R3-proven, 0 conflicts)

#define MFMA1(I, J, A, B) \
  acc[I][J] = __builtin_amdgcn_mfma_f32_16x16x32_bf16(A, B, acc[I][J], 0, 0, 0);

#define MFMAQ(BASE)                                   \
  MFMA1(BASE + 0, 0, aa0, bb0) MFMA1(BASE + 0, 1, aa0, bb1) \
  MFMA1(BASE + 0, 2, aa0, bb2) MFMA1(BASE + 0, 3, aa0, bb3) \
  MFMA1(BASE + 1, 0, aa1, bb0) MFMA1(BASE + 1, 1, aa1, bb1) \
  MFMA1(BASE + 1, 2, aa1, bb2) MFMA1(BASE + 1, 3, aa1, bb3) \
  MFMA1(BASE + 2, 0, aa2, bb0) MFMA1(BASE + 2, 1, aa2, bb1) \
  MFMA1(BASE + 2, 2, aa2, bb2) MFMA1(BASE + 2, 3, aa2, bb3) \
  MFMA1(BASE + 3, 0, aa3, bb0) MFMA1(BASE + 3, 1, aa3, bb1) \
  MFMA1(BASE + 3, 2, aa3, bb2) MFMA1(BASE + 3, 3, aa3, bb3)

#define PH_BAR() do {                           \
  __builtin_amdgcn_sched_barrier(0);            \
  __builtin_amdgcn_s_barrier();                 \
  asm volatile("" ::: "memory");                \
  __builtin_amdgcn_sched_barrier(0);            \
} while (0)

#define VM_WAIT4() do {                                   \
  __builtin_amdgcn_sched_barrier(0);                      \
  asm volatile("s_waitcnt vmcnt(4)" ::: "memory");        \
} while (0)

// One BK=64 tile, 4 phases. T = tile index (stages tile T+1 into the other buffer).
#define TILE64(T) do {                                                        \
  const char* bufC = LDSc + ((T) & 1) * 65536;                                \
  char*       bufN = LDSc + (((T) + 1) & 1) * 65536;                          \
  const int stA = (((T) + 1) & 15) * 128;                                     \
  /* ---- ph0: read A(mh0,kb0)+B(kb0); stage A(T+1,kb0) ---- */               \
  aa0 = *(const short8*)(bufC + aRd);                                         \
  aa1 = *(const short8*)(bufC + aRd + 1024);                                  \
  aa2 = *(const short8*)(bufC + aRd + 2048);                                  \
  aa3 = *(const short8*)(bufC + aRd + 3072);                                  \
  bb0 = *(const short8*)(bufC + 32768 + bRd);                                 \
  bb1 = *(const short8*)(bufC + 32768 + bRd + 1024);                          \
  bb2 = *(const short8*)(bufC + 32768 + bRd + 2048);                          \
  bb3 = *(const short8*)(bufC + 32768 + bRd + 3072);                          \
  gll16(srcA0 + stA, bufN + dstOff);                                          \
  gll16(srcA1 + stA, bufN + 8192 + dstOff);                                   \
  PH_BAR();                                                                   \
  __builtin_amdgcn_s_setprio(1); MFMAQ(0) __builtin_amdgcn_s_setprio(0);      \
  PH_BAR();                                                                   \
  /* ---- ph1: read A(mh1,kb0); stage B(T+1,kb0); vmcnt(4) ---- */            \
  aa0 = *(const short8*)(bufC + aRd + 4096);                                  \
  aa1 = *(const short8*)(bufC + aRd + 5120);                                  \
  aa2 = *(const short8*)(bufC + aRd + 6144);                                  \
  aa3 = *(const short8*)(bufC + aRd + 7168);                                  \
  gll16(srcB0 + stA, bufN + 32768 + dstOff);                                  \
  gll16(srcB1 + stA, bufN + 40960 + dstOff);                                  \
  PH_BAR();                                                                   \
  __builtin_amdgcn_s_setprio(1); MFMAQ(4) __builtin_amdgcn_s_setprio(0);      \
  VM_WAIT4();                                                                 \
  PH_BAR();                                                                   \
  /* ---- ph2: read A(mh0,kb1)+B(kb1); stage A(T+1,kb1) ---- */               \
  aa0 = *(const short8*)(bufC + 16384 + aRd);                                 \
  aa1 = *(const short8*)(bufC + 16384 + aRd + 1024);                          \
  aa2 = *(const short8*)(bufC + 16384 + aRd + 2048);                          \
  aa3 = *(const short8*)(bufC + 16384 + aRd + 3072);                          \
  bb0 = *(const short8*)(bufC + 49152 + bRd);                                 \
  bb1 = *(const short8*)(bufC + 49152 + bRd + 1024);                          \
  bb2 = *(const short8*)(bufC + 49152 + bRd + 2048);                          \
  bb3 = *(const short8*)(bufC + 49152 + bRd + 3072);                          \
  gll16(srcA0 + stA + 64, bufN + 16384 + dstOff);                             \
  gll16(srcA1 + stA + 64, bufN + 24576 + dstOff);                             \
  PH_BAR();                                                                   \
  __builtin_amdgcn_s_setprio(1); MFMAQ(0) __builtin_amdgcn_s_setprio(0);      \
  PH_BAR();                                                                   \
  /* ---- ph3: read A(mh1,kb1); stage B(T+1,kb1); vmcnt(4) ---- */            \
  aa0 = *(const short8*)(bufC + 16384 + aRd + 4096);                          \
  aa1 = *(const short8*)(bufC + 16384 + aRd + 5120);                          \
  aa2 = *(const short8*)(bufC + 16384 + aRd + 6144);                          \
  aa3 = *(const short8*)(bufC + 16384 + aRd + 7168);                          \
  gll16(srcB0 + stA + 64, bufN + 49152 + dstOff);                             \
  gll16(srcB1 + stA + 64, bufN + 57344 + dstOff);                             \
  PH_BAR();                                                                   \
  __builtin_amdgcn_s_setprio(1); MFMAQ(4) __builtin_amdgcn_s_setprio(0);      \
  VM_WAIT4();                                                                 \
  PH_BAR();                                                                   \
} while (0)

__global__ __launch_bounds__(512, 2) void k_gemm256(
    const unsigned short* __restrict__ xb,   // [M][K] bf16
    const unsigned short* __restrict__ wb,   // [N][K] bf16
    const float* __restrict__ bias,          // [2d]
    unsigned short* __restrict__ xtb,        // [M][d] bf16
    unsigned short* __restrict__ fbuf,       // [M][d] bf16
    unsigned short* __restrict__ rbuf) {     // [M][d] bf16
  __shared__ char LDS[131072];
  char* LDSc = LDS;

  const int tid  = threadIdx.x;
  const int lane = tid & 63;
  const int wid  = tid >> 6;
  const int wr   = wid >> 2;     // 0..1
  const int wc   = wid & 3;      // 0..3

  // XCD-aware bijective swizzle: 1536 = 8 * 192
  int bid = blockIdx.x;
  int wg = (bid & 7) * 192 + (bid >> 3);
  int mt = wg / 12;
  int nt = wg - mt * 12;
  const int rowBase = mt * 256;
  const int colBase = nt * 256;

  // ds_read bases (16B-slot permutation: phys = slot ^ ((row>>1)&3))
  const int l15 = lane & 15;
  const int sl  = lane >> 4;
  const int ra0 = wr * 128 + l15;
  const int rb0 = wc * 64 + l15;
  const int aRd = ra0 * 64 + (sl ^ ((ra0 >> 1) & 3)) * 16;
  const int bRd = rb0 * 64 + (sl ^ ((rb0 >> 1) & 3)) * 16;

  // staging source bases (inverse permutation on global source, linear LDS dest)
  const int p0i = tid, p1i = 512 + tid;
  const int r0 = p0i >> 2, r1 = p1i >> 2;
  const int s0 = (p0i & 3) ^ ((r0 >> 1) & 3);
  const int s1 = (p1i & 3) ^ ((r1 >> 1) & 3);
  const char* srcA0 = (const char*)xb + (size_t)(rowBase + r0) * 2048 + s0 * 16;
  const char* srcA1 = (const char*)xb + (size_t)(rowBase + r1) * 2048 + s1 * 16;
  const char* srcB0 = (const char*)wb + (size_t)(colBase + r0) * 2048 + s0 * 16;
  const char* srcB1 = (const char*)wb + (size_t)(colBase + r1) * 2048 + s1 * 16;
  const int dstOff = wid * 1024;

  f32x4 acc[8][4];
#pragma unroll
  for (int ii = 0; ii < 8; ++ii)
#pragma unroll
    for (int jj = 0; jj < 4; ++jj)
      acc[ii][jj] = (f32x4){0.f, 0.f, 0.f, 0.f};

  // prologue: stage tile 0 (both K-halves of A and B) into buffer 0
  gll16(srcA0, LDSc + dstOff);
  gll16(srcA1, LDSc + 8192 + dstOff);
  gll16(srcB0, LDSc + 32768 + dstOff);
  gll16(srcB1, LDSc + 40960 + dstOff);
  gll16(srcA0 + 64, LDSc + 16384 + dstOff);
  gll16(srcA1 + 64, LDSc + 24576 + dstOff);
  gll16(srcB0 + 64, LDSc + 49152 + dstOff);
  gll16(srcB1 + 64, LDSc + 57344 + dstOff);
  asm volatile("s_waitcnt vmcnt(0)" ::: "memory");
  __builtin_amdgcn_s_barrier();
  __builtin_amdgcn_sched_barrier(0);

  short8 aa0, aa1, aa2, aa3;
  short8 bb0, bb1, bb2, bb3;

  for (int i = 0; i < 8; ++i) {
    TILE64(2 * i);
    TILE64(2 * i + 1);
  }
  asm volatile("s_waitcnt vmcnt(0)" ::: "memory");

  // epilogue: region 0 -> x_tilde (bf16), 1 -> forget, 2 -> reset
  const int region = colBase >> 10;
#pragma unroll
  for (int qm = 0; qm < 2; ++qm) {
#pragma unroll
    for (int m = 0; m < 4; ++m) {
      int grow = rowBase + wr * 128 + qm * 64 + m * 16 + ((lane >> 4) << 2);
#pragma unroll
      for (int n = 0; n < 4; ++n) {
        int gcol = colBase + wc * 64 + n * 16 + (lane & 15);
        f32x4 v = acc[qm * 4 + m][n];
        if (region == 0) {
#pragma unroll
          for (int j = 0; j < 4; ++j)
            xtb[(size_t)(grow + j) * DDIM + gcol] = f2bf(v[j]);
        } else {
          float bv = bias[gcol - DDIM];
          unsigned short* dst = (region == 1) ? fbuf : rbuf;
          int lcol = gcol - (region << 10);
#pragma unroll
          for (int j = 0; j < 4; ++j) {
            float sg = 1.0f / (1.0f + __expf(-(v[j] + bv)));
            dst[(size_t)(grow + j) * DDIM + lcol] = f2bf(sg);
          }
        }
      }
    }
  }
}

// ---- segmented scan ------------------------------------------------------
// pass 1: per (segment, channel-pair) affine state a = prod f, b = scan from 0

__global__ __launch_bounds__(256) void k_scan1(
    const unsigned short* __restrict__ fbuf,
    const unsigned short* __restrict__ xtb,
    float4* __restrict__ AB) {
  int chp = blockIdx.x * 256 + threadIdx.x;       // 0..8191 channel pairs
  int seg = blockIdx.y;
  size_t base = (size_t)seg * SEGL * CH + chp * 2;
  const unsigned int* fp = (const unsigned int*)(fbuf + base);
  const unsigned int* xp = (const unsigned int*)(xtb + base);
  float a0 = 1.f, a1 = 1.f, b0 = 0.f, b1 = 0.f;
#pragma unroll 8
  for (int s = 0; s < SEGL; ++s) {
    unsigned int fv = fp[(size_t)s * (CH / 2)];
    unsigned int xv = xp[(size_t)s * (CH / 2)];
    float f0 = bf2f((unsigned short)fv), f1 = bf2f((unsigned short)(fv >> 16));
    float x0 = bf2f((unsigned short)xv), x1 = bf2f((unsigned short)(xv >> 16));
    b0 = (b0 - x0) * f0 + x0;  a0 *= f0;
    b1 = (b1 - x1) * f1 + x1;  a1 *= f1;
  }
  AB[(size_t)seg * (CH / 2) + chp] = (float4){a0, b0, a1, b1};
}

// pass 2: scan 32 segment states per channel; emit per-segment c_in and c_last

__global__ __launch_bounds__(256) void k_scan2(
    const float* __restrict__ c0,
    const float4* __restrict__ AB,
    float* __restrict__ Cin,
    float* __restrict__ clast) {
  int chp = blockIdx.x * 256 + threadIdx.x;       // 0..8191
  float2 cc = ((const float2*)c0)[chp];
  float ca = cc.x, cb = cc.y;
#pragma unroll
  for (int s = 0; s < NSEG; ++s) {
    ((float2*)Cin)[(size_t)s * (CH / 2) + chp] = (float2){ca, cb};
    float4 ab = AB[(size_t)s * (CH / 2) + chp];
    ca = ca * ab.x + ab.y;
    cb = cb * ab.z + ab.w;
  }
  ((float2*)clast)[chp] = (float2){ca, cb};
}

// pass 3: recompute c within segment from c_in; emit h

__global__ __launch_bounds__(256) void k_scan3(
    const float* __restrict__ x,
    const unsigned short* __restrict__ fbuf,
    const unsigned short* __restrict__ xtb,
    const unsigned short* __restrict__ rbuf,
    const float* __restrict__ Cin,
    float* __restrict__ h) {
  int chp = blockIdx.x * 256 + threadIdx.x;
  int seg = blockIdx.y;
  float2 cc = ((const float2*)Cin)[(size_t)seg * (CH / 2) + chp];
  float ca = cc.x, cb = cc.y;
  size_t base = (size_t)seg * SEGL * CH + chp * 2;
  const unsigned int* fp = (const unsigned int*)(fbuf + base);
  const unsigned int* tp = (const unsigned int*)(xtb + base);
  const unsigned int* rp = (const unsigned int*)(rbuf + base);
  const float2* xp = (const float2*)(x + base);
  float2* hp = (float2*)(h + base);
#pragma unroll 4
  for (int s = 0; s < SEGL; ++s) {
    unsigned int fv = fp[(size_t)s * (CH / 2)];
    unsigned int tv = tp[(size_t)s * (CH / 2)];
    unsigned int rv = rp[(size_t)s * (CH / 2)];
    float2 xv = xp[(size_t)s * (CH / 2)];
    float f0 = bf2f((unsigned short)fv), f1 = bf2f((unsigned short)(fv >> 16));
    float t0 = bf2f((unsigned short)tv), t1 = bf2f((unsigned short)(tv >> 16));
    float r0 = bf2f((unsigned short)rv), r1 = bf2f((unsigned short)(rv >> 16));
    ca = (ca - t0) * f0 + t0;
    cb = (cb - t1) * f1 + t1;
    float e0 = __expf(-2.f * fabsf(ca));
    float e1 = __expf(-2.f * fabsf(cb));
    float g0 = copysignf((1.f - e0) / (1.f + e0), ca);
    float g1 = copysignf((1.f - e1) / (1.f + e1), cb);
    float h0 = (g0 - xv.x) * r0 + xv.x;
    float h1 = (g1 - xv.y) * r1 + xv.y;
    hp[(size_t)s * (CH / 2)] = (float2){h0, h1};
  }
}

// ---- launch --------------------------------------------------------------

extern "C" void kernel_launch(void* const* d_in, const int* in_sizes, int n_in,
                              void* d_out, int out_size, void* d_ws, size_t ws_size,
                              hipStream_t stream) {
  const float* x    = (const float*)d_in[0];
  const float* w    = (const float*)d_in[1];
  const float* bias = (const float*)d_in[2];
  const float* c0   = (const float*)d_in[3];
  float* out = (float*)d_out;
  char* ws = (char*)d_ws;

  // ws layout (207.6 MB total):
  //   [0, 6.29MB): wb (GEMM weights)  -- after GEMM, reused as AB (4MB) + Cin (2MB)
  unsigned short* wb   = (unsigned short*)(ws);
  float4*         AB   = (float4*)(ws);
  float*          Cin  = (float*)(ws + 4194304);
  unsigned short* xtb  = (unsigned short*)(ws + 6291456);
  unsigned short* fbuf = (unsigned short*)(ws + 73400320);
  unsigned short* rbuf = (unsigned short*)(ws + 140509184);
  // xb (bf16 x, 64MB) lives in d_out's h region (dead until pass 3 rewrites it)
  unsigned short* xb = (unsigned short*)d_out;

  k_convert_x<<<2048, 256, 0, stream>>>((const float4*)x, (ushort4*)xb, MDIM * KDIM / 4);
  k_convert_w<<<(NDIM * KDIM) / 256, 256, 0, stream>>>(w, wb);

  k_gemm256<<<1536, 512, 0, stream>>>(xb, wb, bias, xtb, fbuf, rbuf);

  k_scan1<<<dim3(32, NSEG), 256, 0, stream>>>(fbuf, xtb, AB);
  k_scan2<<<32, 256, 0, stream>>>(c0, AB, Cin, out + (size_t)L_SEQ * CH);
  k_scan3<<<dim3(32, NSEG), 256, 0, stream>>>(x, fbuf, xtb, rbuf, Cin, out);
}

// Round 5
// 407.172 us; speedup vs baseline: 1.7100x; 1.0036x over previous
//
#include <hip/hip_runtime.h>

#define L_SEQ 2048
#define BATCH 16
#define DDIM  1024
#define MDIM  (L_SEQ * BATCH)   // 32768
#define NDIM  (3 * DDIM)        // 3072
#define KDIM  DDIM              // 1024
#define CH    (BATCH * DDIM)    // 16384
#define NSEG  32
#define SEGL  64                // L_SEQ / NSEG

typedef __attribute__((ext_vector_type(8))) short short8;
typedef __attribute__((ext_vector_type(4))) float f32x4;

static __device__ __forceinline__ unsigned short f2bf(float f) {
  unsigned int u = __builtin_bit_cast(unsigned int, f);
  unsigned int lsb = (u >> 16) & 1u;
  u += 0x7fffu + lsb;
  return (unsigned short)(u >> 16);
}
static __device__ __forceinline__ float bf2f(unsigned short s) {
  unsigned int u = ((unsigned int)s) << 16;
  return __builtin_bit_cast(float, u);
}

static __device__ __forceinline__ void gll16(const void* g, void* l) {
  __builtin_amdgcn_global_load_lds(
      (const __attribute__((address_space(1))) unsigned int*)g,
      (__attribute__((address_space(3))) unsigned int*)l, 16, 0, 0);
}

// ---- converters ----------------------------------------------------------

__global__ void k_convert_x(const float4* __restrict__ x, ushort4* __restrict__ xb, int n4) {
  int i = blockIdx.x * blockDim.x + threadIdx.x;
  int stride = gridDim.x * blockDim.x;
  for (; i < n4; i += stride) {
    float4 v = x[i];
    ushort4 o;
    o.x = f2bf(v.x); o.y = f2bf(v.y); o.z = f2bf(v.z); o.w = f2bf(v.w);
    xb[i] = o;
  }
}

// Wb[n][k] = bf16( W[k][colmap(n)] ): regions {xt, f, r} -> contiguous col ranges
__global__ void k_convert_w(const float* __restrict__ w, unsigned short* __restrict__ wb) {
  int gid = blockIdx.x * 256 + threadIdx.x;   // 3072*1024 total
  int k = gid & (KDIM - 1);
  int n = gid >> 10;
  int col = (n < DDIM) ? 3 * n : (n < 2 * DDIM) ? 3 * (n - DDIM) + 1 : 3 * (n - 2 * DDIM) + 2;
  wb[gid] = f2bf(w[(size_t)k * NDIM + col]);
}

// ---- GEMM: 256x256, BK=64, 8 waves, 4-phase counted-vmcnt, minimal fences
// LDS: 2 buffers x 64KB; buffer = { A_kb0 16K | A_kb1 16K | B_kb0 16K | B_kb1 16K }
// each 16K subtile: 256 rows x 64B, 16B-slot permutation slot^((row>>1)&3) (0 conflicts, R3/R4-proven)
// Fencing discipline (m141 lesson): ONLY the two vmcnt(4) asms carry "memory";
// barriers are bare s_barrier; compiler emits its own lgkmcnt for ds_read->MFMA.

#define MFMA1(I, J, A, B) \
  acc[I][J] = __builtin_amdgcn_mfma_f32_16x16x32_bf16(A, B, acc[I][J], 0, 0, 0);

#define MFMAQ(BASE)                                   \
  MFMA1(BASE + 0, 0, aa0, bb0) MFMA1(BASE + 0, 1, aa0, bb1) \
  MFMA1(BASE + 0, 2, aa0, bb2) MFMA1(BASE + 0, 3, aa0, bb3) \
  MFMA1(BASE + 1, 0, aa1, bb0) MFMA1(BASE + 1, 1, aa1, bb1) \
  MFMA1(BASE + 1, 2, aa1, bb2) MFMA1(BASE + 1, 3, aa1, bb3) \
  MFMA1(BASE + 2, 0, aa2, bb0) MFMA1(BASE + 2, 1, aa2, bb1) \
  MFMA1(BASE + 2, 2, aa2, bb2) MFMA1(BASE + 2, 3, aa2, bb3) \
  MFMA1(BASE + 3, 0, aa3, bb0) MFMA1(BASE + 3, 1, aa3, bb1) \
  MFMA1(BASE + 3, 2, aa3, bb2) MFMA1(BASE + 3, 3, aa3, bb3)

#define PH_BAR() __builtin_amdgcn_s_barrier()

#define VM_WAIT4() asm volatile("s_waitcnt vmcnt(4)" ::: "memory")

// One BK=64 tile, 4 phases. T = tile index (stages tile T+1 into the other buffer).
#define TILE64(T) do {                                                        \
  const char* bufC = LDSc + ((T) & 1) * 65536;                                \
  char*       bufN = LDSc + (((T) + 1) & 1) * 65536;                          \
  const int stA = (((T) + 1) & 15) * 128;                                     \
  /* ---- ph0: read A(mh0,kb0)+B(kb0); stage A(T+1,kb0) ---- */               \
  aa0 = *(const short8*)(bufC + aRd);                                         \
  aa1 = *(const short8*)(bufC + aRd + 1024);                                  \
  aa2 = *(const short8*)(bufC + aRd + 2048);                                  \
  aa3 = *(const short8*)(bufC + aRd + 3072);                                  \
  bb0 = *(const short8*)(bufC + 32768 + bRd);                                 \
  bb1 = *(const short8*)(bufC + 32768 + bRd + 1024);                          \
  bb2 = *(const short8*)(bufC + 32768 + bRd + 2048);                          \
  bb3 = *(const short8*)(bufC + 32768 + bRd + 3072);                          \
  gll16(srcA0 + stA, bufN + dstOff);                                          \
  gll16(srcA1 + stA, bufN + 8192 + dstOff);                                   \
  PH_BAR();                                                                   \
  __builtin_amdgcn_s_setprio(1); MFMAQ(0) __builtin_amdgcn_s_setprio(0);      \
  PH_BAR();                                                                   \
  /* ---- ph1: read A(mh1,kb0); stage B(T+1,kb0); vmcnt(4) ---- */            \
  aa0 = *(const short8*)(bufC + aRd + 4096);                                  \
  aa1 = *(const short8*)(bufC + aRd + 5120);                                  \
  aa2 = *(const short8*)(bufC + aRd + 6144);                                  \
  aa3 = *(const short8*)(bufC + aRd + 7168);                                  \
  gll16(srcB0 + stA, bufN + 32768 + dstOff);                                  \
  gll16(srcB1 + stA, bufN + 40960 + dstOff);                                  \
  PH_BAR();                                                                   \
  __builtin_amdgcn_s_setprio(1); MFMAQ(4) __builtin_amdgcn_s_setprio(0);      \
  VM_WAIT4();                                                                 \
  PH_BAR();                                                                   \
  /* ---- ph2: read A(mh0,kb1)+B(kb1); stage A(T+1,kb1) ---- */               \
  aa0 = *(const short8*)(bufC + 16384 + aRd);                                 \
  aa1 = *(const short8*)(bufC + 16384 + aRd + 1024);                          \
  aa2 = *(const short8*)(bufC + 16384 + aRd + 2048);                          \
  aa3 = *(const short8*)(bufC + 16384 + aRd + 3072);                          \
  bb0 = *(const short8*)(bufC + 49152 + bRd);                                 \
  bb1 = *(const short8*)(bufC + 49152 + bRd + 1024);                          \
  bb2 = *(const short8*)(bufC + 49152 + bRd + 2048);                          \
  bb3 = *(const short8*)(bufC + 49152 + bRd + 3072);                          \
  gll16(srcA0 + stA + 64, bufN + 16384 + dstOff);                             \
  gll16(srcA1 + stA + 64, bufN + 24576 + dstOff);                             \
  PH_BAR();                                                                   \
  __builtin_amdgcn_s_setprio(1); MFMAQ(0) __builtin_amdgcn_s_setprio(0);      \
  PH_BAR();                                                                   \
  /* ---- ph3: read A(mh1,kb1); stage B(T+1,kb1); vmcnt(4) ---- */            \
  aa0 = *(const short8*)(bufC + 16384 + aRd + 4096);                          \
  aa1 = *(const short8*)(bufC + 16384 + aRd + 5120);                          \
  aa2 = *(const short8*)(bufC + 16384 + aRd + 6144);                          \
  aa3 = *(const short8*)(bufC + 16384 + aRd + 7168);                          \
  gll16(srcB0 + stA + 64, bufN + 49152 + dstOff);                             \
  gll16(srcB1 + stA + 64, bufN + 57344 + dstOff);                             \
  PH_BAR();                                                                   \
  __builtin_amdgcn_s_setprio(1); MFMAQ(4) __builtin_amdgcn_s_setprio(0);      \
  VM_WAIT4();                                                                 \
  PH_BAR();                                                                   \
} while (0)

__global__ __launch_bounds__(512, 2) void k_gemm256(
    const unsigned short* __restrict__ xb,   // [M][K] bf16
    const unsigned short* __restrict__ wb,   // [N][K] bf16
    const float* __restrict__ bias,          // [2d]
    unsigned short* __restrict__ xtb,        // [M][d] bf16
    unsigned short* __restrict__ fbuf,       // [M][d] bf16
    unsigned short* __restrict__ rbuf) {     // [M][d] bf16
  __shared__ char LDS[131072];
  char* LDSc = LDS;

  const int tid  = threadIdx.x;
  const int lane = tid & 63;
  const int wid  = tid >> 6;
  const int wr   = wid >> 2;     // 0..1
  const int wc   = wid & 3;      // 0..3

  // XCD-aware bijective swizzle: 1536 = 8 * 192
  int bid = blockIdx.x;
  int wg = (bid & 7) * 192 + (bid >> 3);
  int mt = wg / 12;
  int nt = wg - mt * 12;
  const int rowBase = mt * 256;
  const int colBase = nt * 256;

  // ds_read bases (16B-slot permutation: phys = slot ^ ((row>>1)&3))
  const int l15 = lane & 15;
  const int sl  = lane >> 4;
  const int ra0 = wr * 128 + l15;
  const int rb0 = wc * 64 + l15;
  const int aRd = ra0 * 64 + (sl ^ ((ra0 >> 1) & 3)) * 16;
  const int bRd = rb0 * 64 + (sl ^ ((rb0 >> 1) & 3)) * 16;

  // staging source bases (inverse permutation on global source, linear LDS dest)
  const int p0i = tid, p1i = 512 + tid;
  const int r0 = p0i >> 2, r1 = p1i >> 2;
  const int s0 = (p0i & 3) ^ ((r0 >> 1) & 3);
  const int s1 = (p1i & 3) ^ ((r1 >> 1) & 3);
  const char* srcA0 = (const char*)xb + (size_t)(rowBase + r0) * 2048 + s0 * 16;
  const char* srcA1 = (const char*)xb + (size_t)(rowBase + r1) * 2048 + s1 * 16;
  const char* srcB0 = (const char*)wb + (size_t)(colBase + r0) * 2048 + s0 * 16;
  const char* srcB1 = (const char*)wb + (size_t)(colBase + r1) * 2048 + s1 * 16;
  const int dstOff = wid * 1024;

  f32x4 acc[8][4];
#pragma unroll
  for (int ii = 0; ii < 8; ++ii)
#pragma unroll
    for (int jj = 0; jj < 4; ++jj)
      acc[ii][jj] = (f32x4){0.f, 0.f, 0.f, 0.f};

  // prologue: stage tile 0 (both K-halves of A and B) into buffer 0
  gll16(srcA0, LDSc + dstOff);
  gll16(srcA1, LDSc + 8192 + dstOff);
  gll16(srcB0, LDSc + 32768 + dstOff);
  gll16(srcB1, LDSc + 40960 + dstOff);
  gll16(srcA0 + 64, LDSc + 16384 + dstOff);
  gll16(srcA1 + 64, LDSc + 24576 + dstOff);
  gll16(srcB0 + 64, LDSc + 49152 + dstOff);
  gll16(srcB1 + 64, LDSc + 57344 + dstOff);
  asm volatile("s_waitcnt vmcnt(0)" ::: "memory");
  __builtin_amdgcn_s_barrier();

  short8 aa0, aa1, aa2, aa3;
  short8 bb0, bb1, bb2, bb3;

  for (int i = 0; i < 8; ++i) {
    TILE64(2 * i);
    TILE64(2 * i + 1);
  }
  asm volatile("s_waitcnt vmcnt(0)" ::: "memory");

  // epilogue: region 0 -> x_tilde (bf16), 1 -> forget, 2 -> reset
  const int region = colBase >> 10;
#pragma unroll
  for (int qm = 0; qm < 2; ++qm) {
#pragma unroll
    for (int m = 0; m < 4; ++m) {
      int grow = rowBase + wr * 128 + qm * 64 + m * 16 + ((lane >> 4) << 2);
#pragma unroll
      for (int n = 0; n < 4; ++n) {
        int gcol = colBase + wc * 64 + n * 16 + (lane & 15);
        f32x4 v = acc[qm * 4 + m][n];
        if (region == 0) {
#pragma unroll
          for (int j = 0; j < 4; ++j)
            xtb[(size_t)(grow + j) * DDIM + gcol] = f2bf(v[j]);
        } else {
          float bv = bias[gcol - DDIM];
          unsigned short* dst = (region == 1) ? fbuf : rbuf;
          int lcol = gcol - (region << 10);
#pragma unroll
          for (int j = 0; j < 4; ++j) {
            float sg = 1.0f / (1.0f + __expf(-(v[j] + bv)));
            dst[(size_t)(grow + j) * DDIM + lcol] = f2bf(sg);
          }
        }
      }
    }
  }
}

// ---- segmented scan ------------------------------------------------------
// pass 1: per (segment, channel-pair) affine state a = prod f, b = scan from 0

__global__ __launch_bounds__(256) void k_scan1(
    const unsigned short* __restrict__ fbuf,
    const unsigned short* __restrict__ xtb,
    float4* __restrict__ AB) {
  int chp = blockIdx.x * 256 + threadIdx.x;       // 0..8191 channel pairs
  int seg = blockIdx.y;
  size_t base = (size_t)seg * SEGL * CH + chp * 2;
  const unsigned int* fp = (const unsigned int*)(fbuf + base);
  const unsigned int* xp = (const unsigned int*)(xtb + base);
  float a0 = 1.f, a1 = 1.f, b0 = 0.f, b1 = 0.f;
#pragma unroll 8
  for (int s = 0; s < SEGL; ++s) {
    unsigned int fv = fp[(size_t)s * (CH / 2)];
    unsigned int xv = xp[(size_t)s * (CH / 2)];
    float f0 = bf2f((unsigned short)fv), f1 = bf2f((unsigned short)(fv >> 16));
    float x0 = bf2f((unsigned short)xv), x1 = bf2f((unsigned short)(xv >> 16));
    b0 = (b0 - x0) * f0 + x0;  a0 *= f0;
    b1 = (b1 - x1) * f1 + x1;  a1 *= f1;
  }
  AB[(size_t)seg * (CH / 2) + chp] = (float4){a0, b0, a1, b1};
}

// pass 2: scan 32 segment states per channel; emit per-segment c_in and c_last

__global__ __launch_bounds__(256) void k_scan2(
    const float* __restrict__ c0,
    const float4* __restrict__ AB,
    float* __restrict__ Cin,
    float* __restrict__ clast) {
  int chp = blockIdx.x * 256 + threadIdx.x;       // 0..8191
  float2 cc = ((const float2*)c0)[chp];
  float ca = cc.x, cb = cc.y;
#pragma unroll
  for (int s = 0; s < NSEG; ++s) {
    ((float2*)Cin)[(size_t)s * (CH / 2) + chp] = (float2){ca, cb};
    float4 ab = AB[(size_t)s * (CH / 2) + chp];
    ca = ca * ab.x + ab.y;
    cb = cb * ab.z + ab.w;
  }
  ((float2*)clast)[chp] = (float2){ca, cb};
}

// pass 3: recompute c within segment from c_in; emit h

__global__ __launch_bounds__(256) void k_scan3(
    const float* __restrict__ x,
    const unsigned short* __restrict__ fbuf,
    const unsigned short* __restrict__ xtb,
    const unsigned short* __restrict__ rbuf,
    const float* __restrict__ Cin,
    float* __restrict__ h) {
  int chp = blockIdx.x * 256 + threadIdx.x;
  int seg = blockIdx.y;
  float2 cc = ((const float2*)Cin)[(size_t)seg * (CH / 2) + chp];
  float ca = cc.x, cb = cc.y;
  size_t base = (size_t)seg * SEGL * CH + chp * 2;
  const unsigned int* fp = (const unsigned int*)(fbuf + base);
  const unsigned int* tp = (const unsigned int*)(xtb + base);
  const unsigned int* rp = (const unsigned int*)(rbuf + base);
  const float2* xp = (const float2*)(x + base);
  float2* hp = (float2*)(h + base);
#pragma unroll 4
  for (int s = 0; s < SEGL; ++s) {
    unsigned int fv = fp[(size_t)s * (CH / 2)];
    unsigned int tv = tp[(size_t)s * (CH / 2)];
    unsigned int rv = rp[(size_t)s * (CH / 2)];
    float2 xv = xp[(size_t)s * (CH / 2)];
    float f0 = bf2f((unsigned short)fv), f1 = bf2f((unsigned short)(fv >> 16));
    float t0 = bf2f((unsigned short)tv), t1 = bf2f((unsigned short)(tv >> 16));
    float r0 = bf2f((unsigned short)rv), r1 = bf2f((unsigned short)(rv >> 16));
    ca = (ca - t0) * f0 + t0;
    cb = (cb - t1) * f1 + t1;
    float e0 = __expf(-2.f * fabsf(ca));
    float e1 = __expf(-2.f * fabsf(cb));
    float g0 = copysignf((1.f - e0) / (1.f + e0), ca);
    float g1 = copysignf((1.f - e1) / (1.f + e1), cb);
    float h0 = (g0 - xv.x) * r0 + xv.x;
    float h1 = (g1 - xv.y) * r1 + xv.y;
    hp[(size_t)s * (CH / 2)] = (float2){h0, h1};
  }
}

// ---- launch --------------------------------------------------------------

extern "C" void kernel_launch(void* const* d_in, const int* in_sizes, int n_in,
                              void* d_out, int out_size, void* d_ws, size_t ws_size,
                              hipStream_t stream) {
  const float* x    = (const float*)d_in[0];
  const float* w    = (const float*)d_in[1];
  const float* bias = (const float*)d_in[2];
  const float* c0   = (const float*)d_in[3];
  float* out = (float*)d_out;
  char* ws = (char*)d_ws;

  // ws layout (207.6 MB total):
  //   [0, 6.29MB): wb (GEMM weights)  -- after GEMM, reused as AB (4MB) + Cin (2MB)
  unsigned short* wb   = (unsigned short*)(ws);
  float4*         AB   = (float4*)(ws);
  float*          Cin  = (float*)(ws + 4194304);
  unsigned short* xtb  = (unsigned short*)(ws + 6291456);
  unsigned short* fbuf = (unsigned short*)(ws + 73400320);
  unsigned short* rbuf = (unsigned short*)(ws + 140509184);
  // xb (bf16 x, 64MB) lives in d_out's h region (dead until pass 3 rewrites it)
  unsigned short* xb = (unsigned short*)d_out;

  k_convert_x<<<2048, 256, 0, stream>>>((const float4*)x, (ushort4*)xb, MDIM * KDIM / 4);
  k_convert_w<<<(NDIM * KDIM) / 256, 256, 0, stream>>>(w, wb);

  k_gemm256<<<1536, 512, 0, stream>>>(xb, wb, bias, xtb, fbuf, rbuf);

  k_scan1<<<dim3(32, NSEG), 256, 0, stream>>>(fbuf, xtb, AB);
  k_scan2<<<32, 256, 0, stream>>>(c0, AB, Cin, out + (size_t)L_SEQ * CH);
  k_scan3<<<dim3(32, NSEG), 256, 0, stream>>>(x, fbuf, xtb, rbuf, Cin, out);
}